// Round 20
// baseline (81.369 us; speedup 1.0000x reference)
//
#include <hip/hip_runtime.h>

// Problem constants (match reference)
#define VOCABN 100
#define EMBEDN 16
#define STATEN 7
#define OUTN   10
#define BATCHN 4096
#define SEQT   512
#define L2E 1.44269504088896340736f

typedef float v2f __attribute__((ext_vector_type(2)));

__device__ __forceinline__ float fexp2(float x){ float r; asm("v_exp_f32 %0, %1":"=v"(r):"v"(x)); return r; }
__device__ __forceinline__ float frcp (float x){ float r; asm("v_rcp_f32 %0, %1":"=v"(r):"v"(x)); return r; }
#define SBAR() __builtin_amdgcn_sched_barrier(0)

// DPP helpers. row_ror:n = 0x120+n (16-lane ring, parity-preserving for even n);
// quad_perm [1,0,3,2] = 0xB1 (parity-partner exchange).
template<int C> __device__ __forceinline__ int dppi(int x){
  return __builtin_amdgcn_update_dpp(0, x, C, 0xF, 0xF, true);
}
template<int C> __device__ __forceinline__ float dppf(float x){
  return __int_as_float(__builtin_amdgcn_update_dpp(0, __float_as_int(x), C, 0xF, 0xF, true));
}

// ---------------------------------------------------------------------------
// Kernel A (r14): embW2[v][pos] = pre-scaled gate pre-activations, pos=s*2+p.
// p0 -> (i,f), p1 -> (g,o). Scales i,f,o: -L2E; g: +2L2E. Pad s=7 -> 0.
// ---------------------------------------------------------------------------
__global__ void embw_kernel(const float* __restrict__ emb, const float* __restrict__ W,
                            const float* __restrict__ b, float* __restrict__ embw){
  int v = blockIdx.x, j = threadIdx.x;          // j 0..31
  int pos = j >> 1, g2 = j & 1;
  int s = pos >> 1, p = pos & 1, gate = p*2 + g2;
  float val = 0.0f;
  if (s < STATEN) {
    int col = gate*STATEN + s;
    val = b[col];
    #pragma unroll
    for (int e = 0; e < EMBEDN; ++e) val = fmaf(emb[v*EMBEDN+e], W[e*28+col], val);
    val *= (gate == 2) ? (2.0f*L2E) : (-L2E);
  }
  embw[v*32 + pos*2 + g2] = val;
}

// ---------------------------------------------------------------------------
// Kernel B: EXACT r14/r19 datapath, with sched_barrier(0)-ENFORCED latency
// windows (r19 showed source order alone is ignored; VALUBusy says the
// compiler fills ~none of the 4x ~40cy trans windows). Three pinned gaps:
//  GAP1 (exp2(zA/zB) -> rcp):  flush first-half  (~12-20 indep instr)
//  GAP2 (rcp -> gg_s/go_x):    prefetch pair
//  GAP3 (exp2(Cc) -> rcpC):    flush second-half (~8-16 indep instr)
// Ring float4 loads now ISSUE at u0 and are first USED at u1 (~400cy later)
// -> removes r14's amortized u0 lgkm stall. Zero arithmetic change.
// ---------------------------------------------------------------------------
__global__ void __launch_bounds__(64,1)
lstm_kernel(const int* __restrict__ tokens, const float* __restrict__ embw,
            const float* __restrict__ U, const float* __restrict__ Wd,
            const float* __restrict__ bdv, float* __restrict__ out){
  __shared__ float embW_s[VOCABN*32];   // 12.8 KB
  __shared__ int   tok_s[4*520];        // 8.3 KB (+pads for over-read)
  __shared__ float hbuf[2*8*48 + 64];   // 3.3 KB: 2 slots x [u8][48] + dummy

  const int L = threadIdx.x;
  const int b0 = blockIdx.x*4;

  for (int i=L;i<VOCABN*8;i+=64) ((float4*)embW_s)[i]=((const float4*)embw)[i];
  for (int i=L;i<512;i+=64){ int r=i>>7,c4=i&127;
    int4 v=((const int4*)(tokens+(size_t)(b0+r)*SEQT))[c4];
    *((int4*)&tok_s[r*520+c4*4])=v; }
  if (L<4){ tok_s[L*520+512]=0; tok_s[L*520+513]=0;
            tok_s[L*520+514]=0; tok_s[L*520+515]=0; }
  __syncthreads();

  const int pos=L&15, ch=L>>4, s=pos>>1, p=pos&1;
  const int pos2=pos*2;

  // sigma discovery: run own state id through the exact broadcast net
  int sg[8];
  sg[0]=s;
  sg[1]=dppi<0x122>(s); sg[2]=dppi<0x124>(s); sg[3]=dppi<0x126>(s);
  sg[4]=dppi<0x128>(s); sg[5]=dppi<0x12A>(s); sg[6]=dppi<0x12C>(s); sg[7]=dppi<0x12E>(s);

  // recurrent weights: packed {colA,colB}, pre-permuted by sigma, pre-scaled
  v2f Ucp[8];
  {
    const int gA=p*2, gB=p*2+1;
    const float sA = (gA==2)?(2.0f*L2E):(-L2E);
    const float sB = (gB==2)?(2.0f*L2E):(-L2E);
    #pragma unroll
    for (int k=0;k<8;++k){
      int sk=sg[k]; bool vld=(sk<STATEN)&&(s<STATEN);
      Ucp[k].x = vld ? U[sk*28+gA*7+s]*sA : 0.0f;
      Ucp[k].y = vld ? U[sk*28+gB*7+s]*sB : 0.0f;
    }
  }
  // dense weights, NATURAL state order (ring h unpermuted), L2E-scaled
  float Wdc[8][5], bdr[5];
  #pragma unroll
  for (int k=0;k<8;++k)
    #pragma unroll
    for (int o=0;o<5;++o) Wdc[k][o] = (k<STATEN)? Wd[k*10+p*5+o]*L2E : 0.0f;
  #pragma unroll
  for (int o=0;o<5;++o) bdr[o]=bdv[p*5+o]*L2E;

  const int* trow=&tok_s[ch*520];
  float* outp = out + ((size_t)(b0+ch)*SEQT + s)*OUTN + p*5;  // s doubles as flush-timestep

  // h-ring lane addresses: even lanes carry the real h; odd lanes write a
  // distinct dummy strip (bank-clean).
  const int loff = p ? (2*8*48 + L) : (ch*8 + s);
  const int roff = s*48 + ch*8;            // flush read: [tq=s][ch*8..+7]

  float lg[5], ee[5];
  float sA4=0.0f, smq=0.0f, rs=0.0f;
  float4 LA = make_float4(0,0,0,0), LB = make_float4(0,0,0,0);

  // depth-2 prefetch queues. State at top of step t:
  //   pf0=row(t), pf1=row(t+1), tkA=tok(t+2), tkB=tok(t+3).
  int tkA = trow[2];
  int tkB = trow[3];
  v2f pf0 = *(const v2f*)&embW_s[trow[0]*32 + pos2];
  v2f pf1 = *(const v2f*)&embW_s[trow[1]*32 + pos2];
  float Cc=0.0f, h=0.0f;

  for (int m=0;m<64;++m){
    float* wv = hbuf + (m&1)*384 + loff;             // write slot (m&1)
    const float* rv = hbuf + ((m+1)&1)*384 + roff;   // read slot of octet m-1
    #pragma unroll
    for (int u=0;u<8;++u){
      const int t = m*8+u;

      // broadcast h_{t-1} across the 16-lane chain (depth-1 DPP net)
      float r0=h;
      float r1=dppf<0x122>(h), r2=dppf<0x124>(h), r3=dppf<0x126>(h);
      float r4=dppf<0x128>(h), r5=dppf<0x12A>(h), r6=dppf<0x12C>(h), r7=dppf<0x12E>(h);

      // z = embW'[tok] + h @ U'  (v2f packed tree — r5-validated)
      v2f z01=__builtin_elementwise_fma((v2f){r1,r1},Ucp[1],
              __builtin_elementwise_fma((v2f){r0,r0},Ucp[0],pf0));
      v2f z23=__builtin_elementwise_fma((v2f){r3,r3},Ucp[3],(v2f){r2,r2}*Ucp[2]);
      v2f z45=__builtin_elementwise_fma((v2f){r5,r5},Ucp[5],(v2f){r4,r4}*Ucp[4]);
      v2f z67=__builtin_elementwise_fma((v2f){r7,r7},Ucp[7],(v2f){r6,r6}*Ucp[6]);
      v2f zv=(z01+z23)+(z45+z67);

      // gate exp2 ISSUE
      float eA = fexp2(zv.x);
      float eB = fexp2(zv.y);
      SBAR();
      // ================= GAP1: flush first-half (pinned) =================
      if (u==0){ LA = *(const float4*)rv; }             // issue only; used at u1
      if (u==1){
        float a0=bdr[0], a1=bdr[1];
        a0=__builtin_fmaf(LA.x,Wdc[0][0],a0); a1=__builtin_fmaf(LA.x,Wdc[0][1],a1);
        a0=__builtin_fmaf(LA.y,Wdc[1][0],a0); a1=__builtin_fmaf(LA.y,Wdc[1][1],a1);
        a0=__builtin_fmaf(LA.z,Wdc[2][0],a0); a1=__builtin_fmaf(LA.z,Wdc[2][1],a1);
        a0=__builtin_fmaf(LA.w,Wdc[3][0],a0); a1=__builtin_fmaf(LA.w,Wdc[3][1],a1);
        lg[0]=a0; lg[1]=a1; }
      if (u==2){
        float a2=bdr[2], a3=bdr[3];
        a2=__builtin_fmaf(LA.x,Wdc[0][2],a2); a3=__builtin_fmaf(LA.x,Wdc[0][3],a3);
        a2=__builtin_fmaf(LA.y,Wdc[1][2],a2); a3=__builtin_fmaf(LA.y,Wdc[1][3],a3);
        a2=__builtin_fmaf(LA.z,Wdc[2][2],a2); a3=__builtin_fmaf(LA.z,Wdc[2][3],a3);
        a2=__builtin_fmaf(LA.w,Wdc[3][2],a2); a3=__builtin_fmaf(LA.w,Wdc[3][3],a3);
        lg[2]=a2; lg[3]=a3; }
      if (u==3){
        float a4=bdr[4];
        a4=__builtin_fmaf(LA.x,Wdc[0][4],a4); a4=__builtin_fmaf(LA.y,Wdc[1][4],a4);
        a4=__builtin_fmaf(LA.z,Wdc[2][4],a4); a4=__builtin_fmaf(LA.w,Wdc[3][4],a4);
        lg[4]=a4; }
      if (u==4){
        ee[0]=fexp2(lg[0]); ee[1]=fexp2(lg[1]); ee[2]=fexp2(lg[2]); }
      if (u==5){ sA4=(ee[0]+ee[1])+(ee[2]+ee[3]); }
      if (u==6){ rs=frcp(smq + dppf<0xB1>(smq)); }      // partner combine
      if (u==7){
        if (m>=1){
          outp[0]=ee[0]*rs; outp[1]=ee[1]*rs; outp[2]=ee[2]*rs;
        } }
      SBAR();
      // gate rcp (uses eA/eB after GAP1)
      float gA=frcp(1.0f+eA);
      float gB=frcp(1.0f+eB);
      SBAR();
      // ================= GAP2: prefetch (pinned) =========================
      v2f pf2 = *(const v2f*)&embW_s[tkA*32 + pos2];    // row(t+2)
      int tkC = trow[t+4];                              // tok(t+4), pads 512..515
      SBAR();
      float gg_s=__builtin_fmaf(gA,-4.0f*L2E,2.0f*L2E); // 2L2E*tanh(zg) on p1
      float gg_x=dppf<0xB1>(gg_s);                      // p0 <- p1
      float go_x=dppf<0xB1>(gB);                        // p0 <- p1's o
      Cc=__builtin_fmaf(gB,Cc,gA*gg_x);                 // valid on p0 (2L2E*c)
      float eC=fexp2(Cc);                               // ISSUE
      SBAR();
      // ================= GAP3: flush second-half (pinned) ================
      if (u==0){ LB = *(const float4*)(rv+4); }         // issue only; used at u1
      if (u==1){
        float a0=lg[0], a1=lg[1];
        a0=__builtin_fmaf(LB.x,Wdc[4][0],a0); a1=__builtin_fmaf(LB.x,Wdc[4][1],a1);
        a0=__builtin_fmaf(LB.y,Wdc[5][0],a0); a1=__builtin_fmaf(LB.y,Wdc[5][1],a1);
        a0=__builtin_fmaf(LB.z,Wdc[6][0],a0); a1=__builtin_fmaf(LB.z,Wdc[6][1],a1);
        lg[0]=a0; lg[1]=a1; }                           // Wdc[7]=0: skip LB.w
      if (u==2){
        float a2=lg[2], a3=lg[3];
        a2=__builtin_fmaf(LB.x,Wdc[4][2],a2); a3=__builtin_fmaf(LB.x,Wdc[4][3],a3);
        a2=__builtin_fmaf(LB.y,Wdc[5][2],a2); a3=__builtin_fmaf(LB.y,Wdc[5][3],a3);
        a2=__builtin_fmaf(LB.z,Wdc[6][2],a2); a3=__builtin_fmaf(LB.z,Wdc[6][3],a3);
        lg[2]=a2; lg[3]=a3; }
      if (u==3){
        float a4=lg[4];
        a4=__builtin_fmaf(LB.x,Wdc[4][4],a4); a4=__builtin_fmaf(LB.y,Wdc[5][4],a4);
        a4=__builtin_fmaf(LB.z,Wdc[6][4],a4);
        lg[4]=a4; }
      if (u==4){ ee[3]=fexp2(lg[3]); ee[4]=fexp2(lg[4]); }
      if (u==5){ smq=sA4+ee[4]; }
      if (u==7){
        if (m>=1){
          outp[3]=ee[3]*rs; outp[4]=ee[4]*rs;
          outp += 8*OUTN;
        } }
      SBAR();
      // cell rcp (uses eC after GAP3) + tail
      float rcpC=frcp(1.0f+eC);                         // valid on p0
      float rcpC_x=dppf<0xB1>(rcpC);                    // p1 <- p0
      float go_u = p ? gB     : go_x;
      float rc_u = p ? rcpC_x : rcpC;
      h=__builtin_fmaf(-2.0f*go_u, rc_u, go_u);         // h = o*tanh(c)

      wv[u*48] = h;                                     // publish h_t (imm offset)

      pf0=pf1; pf1=pf2; tkA=tkB; tkB=tkC;
    }
  }

  // ---- epilogue: flush octet 63 (ring slot 1) ----
  {
    const float* rv = hbuf + 384 + roff;   // (63&1)=1
    float4 a = *(const float4*)rv;
    float4 bq = *(const float4*)(rv+4);
    float hcv[8]={a.x,a.y,a.z,a.w,bq.x,bq.y,bq.z,bq.w};
    #pragma unroll
    for (int o=0;o<5;++o){ float aa=bdr[o];
      #pragma unroll
      for (int k=0;k<8;++k) aa=__builtin_fmaf(hcv[k],Wdc[k][o],aa);
      lg[o]=aa; }
    float e0=fexp2(lg[0]), e1=fexp2(lg[1]), e2=fexp2(lg[2]),
          e3=fexp2(lg[3]), e4=fexp2(lg[4]);
    float sm=((e0+e1)+(e2+e3))+e4;
    float r=frcp(sm + dppf<0xB1>(sm));
    outp[0]=e0*r; outp[1]=e1*r; outp[2]=e2*r; outp[3]=e3*r; outp[4]=e4*r;
  }
}

// ---------------------------------------------------------------------------
// inputs: 0 tokens 1 emb 2 W 3 U 4 b 5 Wd 6 bd ; out f32 B*T*10.
// d_ws: 12800 B for the pre-scaled embW table (rewritten every call).
// ---------------------------------------------------------------------------
extern "C" void kernel_launch(void* const* d_in, const int* in_sizes, int n_in,
                              void* d_out, int out_size, void* d_ws, size_t ws_size,
                              hipStream_t stream) {
  const int*   tokens = (const int*)d_in[0];
  const float* emb    = (const float*)d_in[1];
  const float* W      = (const float*)d_in[2];
  const float* U      = (const float*)d_in[3];
  const float* b      = (const float*)d_in[4];
  const float* Wd     = (const float*)d_in[5];
  const float* bd     = (const float*)d_in[6];
  float* outp = (float*)d_out;
  float* embw = (float*)d_ws;

  embw_kernel<<<dim3(VOCABN), dim3(32), 0, stream>>>(emb, W, b, embw);
  lstm_kernel<<<dim3(BATCHN/4), dim3(64), 0, stream>>>(tokens, embw, U, Wd, bd, outp);
}

// Round 21
// 79.232 us; speedup vs baseline: 1.0270x; 1.0270x over previous
//
#include <hip/hip_runtime.h>

// Problem constants (match reference)
#define VOCABN 100
#define EMBEDN 16
#define STATEN 7
#define OUTN   10
#define BATCHN 4096
#define SEQT   512
#define L2E 1.44269504088896340736f

typedef float v2f __attribute__((ext_vector_type(2)));

__device__ __forceinline__ float fexp2(float x){ float r; asm("v_exp_f32 %0, %1":"=v"(r):"v"(x)); return r; }
__device__ __forceinline__ float frcp (float x){ float r; asm("v_rcp_f32 %0, %1":"=v"(r):"v"(x)); return r; }

// DPP helpers. row_ror:n = 0x120+n (16-lane ring, parity-preserving for even n);
// quad_perm [1,0,3,2] = 0xB1 (parity-partner exchange).
template<int C> __device__ __forceinline__ int dppi(int x){
  return __builtin_amdgcn_update_dpp(0, x, C, 0xF, 0xF, true);
}
template<int C> __device__ __forceinline__ float dppf(float x){
  return __int_as_float(__builtin_amdgcn_update_dpp(0, __float_as_int(x), C, 0xF, 0xF, true));
}

// ---------------------------------------------------------------------------
// Kernel A: embW2[v][pos] = pre-scaled gate pre-activations, pos = s*2+p.
// p0 -> (i,f), p1 -> (g,o). Scales i,f,o: -L2E; g: +2L2E. Pad s=7 -> 0.
// ---------------------------------------------------------------------------
__global__ void embw_kernel(const float* __restrict__ emb, const float* __restrict__ W,
                            const float* __restrict__ b, float* __restrict__ embw){
  int v = blockIdx.x, j = threadIdx.x;          // j 0..31
  int pos = j >> 1, g2 = j & 1;
  int s = pos >> 1, p = pos & 1, gate = p*2 + g2;
  float val = 0.0f;
  if (s < STATEN) {
    int col = gate*STATEN + s;
    val = b[col];
    #pragma unroll
    for (int e = 0; e < EMBEDN; ++e) val = fmaf(emb[v*EMBEDN+e], W[e*28+col], val);
    val *= (gate == 2) ? (2.0f*L2E) : (-L2E);
  }
  embw[v*32 + pos*2 + g2] = val;
}

// ---------------------------------------------------------------------------
// Kernel B: CHAMPION (round 14; 78.7us bench / 90us rocprof, absmax 4.88e-4).
// r3 structure (1024 blocks x 64 thr, 4 chains x 16 lanes, parity-split
// gates), instruction-minimized per the round-13/15 cadence findings
// (wall = ~2cy/instr VALU + 12cy/trans issue + ~224cy serial path):
//  - z-tree: v2f packed (v_pk_fma_f32), 11 ops.
//  - LDS octet-ring h publication (no register capture): even lanes write h,
//    odd lanes a dummy strip; flush reads 2x float4 once per octet, natural
//    state order.
//  - depth-1 prefetch: token via immediate-offset ds_read, embW row one
//    step ahead.
//  - softmax max-sub dropped (logits bounded).
// Flush staged across the 8 steps of the next octet: u0 load, u1..3 logits,
// u4 exp, u5 sum, u6 partner-sum+rcp, u7 store.
// 20 rounds of structural experiments (P/C waves, ILP, TLP, Pade, zero-LDS,
// reordering, sched_barrier pins) bracket this as the issue+path floor.
// ---------------------------------------------------------------------------
__global__ void __launch_bounds__(64,1)
lstm_kernel(const int* __restrict__ tokens, const float* __restrict__ embw,
            const float* __restrict__ U, const float* __restrict__ Wd,
            const float* __restrict__ bdv, float* __restrict__ out){
  __shared__ float embW_s[VOCABN*32];   // 12.8 KB
  __shared__ int   tok_s[4*520];        // 8.3 KB (+pads for over-read)
  __shared__ float hbuf[2*8*48 + 64];   // 3.3 KB: 2 slots x [u8][48] + dummy

  const int L = threadIdx.x;
  const int b0 = blockIdx.x*4;

  for (int i=L;i<VOCABN*8;i+=64) ((float4*)embW_s)[i]=((const float4*)embw)[i];
  for (int i=L;i<512;i+=64){ int r=i>>7,c4=i&127;
    int4 v=((const int4*)(tokens+(size_t)(b0+r)*SEQT))[c4];
    *((int4*)&tok_s[r*520+c4*4])=v; }
  if (L<4){ tok_s[L*520+512]=0; tok_s[L*520+513]=0; tok_s[L*520+514]=0; }
  __syncthreads();

  const int pos=L&15, ch=L>>4, s=pos>>1, p=pos&1;
  const int pos2=pos*2;

  // sigma discovery: run own state id through the exact broadcast net
  int sg[8];
  sg[0]=s;
  sg[1]=dppi<0x122>(s); sg[2]=dppi<0x124>(s); sg[3]=dppi<0x126>(s);
  sg[4]=dppi<0x128>(s); sg[5]=dppi<0x12A>(s); sg[6]=dppi<0x12C>(s); sg[7]=dppi<0x12E>(s);

  // recurrent weights: packed {colA,colB}, pre-permuted by sigma, pre-scaled
  v2f Ucp[8];
  {
    const int gA=p*2, gB=p*2+1;
    const float sA = (gA==2)?(2.0f*L2E):(-L2E);
    const float sB = (gB==2)?(2.0f*L2E):(-L2E);
    #pragma unroll
    for (int k=0;k<8;++k){
      int sk=sg[k]; bool vld=(sk<STATEN)&&(s<STATEN);
      Ucp[k].x = vld ? U[sk*28+gA*7+s]*sA : 0.0f;
      Ucp[k].y = vld ? U[sk*28+gB*7+s]*sB : 0.0f;
    }
  }
  // dense weights, NATURAL state order (ring h unpermuted), L2E-scaled
  float Wdc[8][5], bdr[5];
  #pragma unroll
  for (int k=0;k<8;++k)
    #pragma unroll
    for (int o=0;o<5;++o) Wdc[k][o] = (k<STATEN)? Wd[k*10+p*5+o]*L2E : 0.0f;
  #pragma unroll
  for (int o=0;o<5;++o) bdr[o]=bdv[p*5+o]*L2E;

  const int* trow=&tok_s[ch*520];
  float* outp = out + ((size_t)(b0+ch)*SEQT + s)*OUTN + p*5;  // s doubles as flush-timestep

  // h-ring lane addresses: even lanes carry the real h; odd lanes write a
  // distinct dummy strip (bank-clean).
  const int loff = p ? (2*8*48 + L) : (ch*8 + s);
  const int roff = s*48 + ch*8;            // flush read: [tq=s][ch*8..+7]

  float hc[8], lg[5], ee[5];
  float smq=0.0f, rs=0.0f;

  // depth-1 prefetch queues
  int tok_next = trow[1];
  v2f pf0 = *(const v2f*)&embW_s[trow[0]*32 + pos2];
  float Cc=0.0f, h=0.0f;

  for (int m=0;m<64;++m){
    const int* trm = trow + m*8;
    float* wv = hbuf + (m&1)*384 + loff;             // write slot (m&1)
    const float* rv = hbuf + ((m+1)&1)*384 + roff;   // read slot of octet m-1
    #pragma unroll
    for (int u=0;u<8;++u){
      // prefetch: token t+2 (imm offset), embW row t+1
      int tokN = trm[u+2];
      v2f pfN = *(const v2f*)&embW_s[tok_next*32 + pos2];

      // broadcast h_{t-1} across the 16-lane chain (depth-1 DPP net)
      float r0=h;
      float r1=dppf<0x122>(h), r2=dppf<0x124>(h), r3=dppf<0x126>(h);
      float r4=dppf<0x128>(h), r5=dppf<0x12A>(h), r6=dppf<0x12C>(h), r7=dppf<0x12E>(h);

      // z = embW'[tok] + h @ U'  (v2f packed tree — r5-validated)
      v2f z01=__builtin_elementwise_fma((v2f){r1,r1},Ucp[1],
              __builtin_elementwise_fma((v2f){r0,r0},Ucp[0],pf0));
      v2f z23=__builtin_elementwise_fma((v2f){r3,r3},Ucp[3],(v2f){r2,r2}*Ucp[2]);
      v2f z45=__builtin_elementwise_fma((v2f){r5,r5},Ucp[5],(v2f){r4,r4}*Ucp[4]);
      v2f z67=__builtin_elementwise_fma((v2f){r7,r7},Ucp[7],(v2f){r6,r6}*Ucp[6]);
      v2f zv=(z01+z23)+(z45+z67);

      // gates: p0: gA=i, gB=f ; p1: gA=rcp-part of g, gB=o
      float gA=frcp(1.0f+fexp2(zv.x));
      float gB=frcp(1.0f+fexp2(zv.y));
      float gg_s=__builtin_fmaf(gA,-4.0f*L2E,2.0f*L2E); // 2L2E*tanh(zg) on p1
      float gg_x=dppf<0xB1>(gg_s);                      // p0 <- p1
      float go_x=dppf<0xB1>(gB);                        // p0 <- p1's o
      Cc=__builtin_fmaf(gB,Cc,gA*gg_x);                 // valid on p0 (2L2E*c)
      float rcpC=frcp(1.0f+fexp2(Cc));                  // valid on p0
      float rcpC_x=dppf<0xB1>(rcpC);                    // p1 <- p0
      float go_u = p ? gB     : go_x;
      float rc_u = p ? rcpC_x : rcpC;
      h=__builtin_fmaf(-2.0f*go_u, rc_u, go_u);         // h = o*tanh(c)

      wv[u*48] = h;                                     // publish h_t (imm offset)

      // ---- staged flush of octet m-1 (reads ring slot ((m+1)&1)) ----
      if (u==0){
        float4 a = *(const float4*)rv;
        float4 bq = *(const float4*)(rv+4);
        hc[0]=a.x; hc[1]=a.y; hc[2]=a.z; hc[3]=a.w;
        hc[4]=bq.x; hc[5]=bq.y; hc[6]=bq.z; hc[7]=bq.w;  // hc[7]*Wdc[7]=0
      }
      if (u==1){
        float a0=bdr[0], a1=bdr[1];
        #pragma unroll
        for (int k=0;k<8;++k){ a0=__builtin_fmaf(hc[k],Wdc[k][0],a0);
                               a1=__builtin_fmaf(hc[k],Wdc[k][1],a1); }
        lg[0]=a0; lg[1]=a1; }
      if (u==2){
        float a2=bdr[2], a3=bdr[3];
        #pragma unroll
        for (int k=0;k<8;++k){ a2=__builtin_fmaf(hc[k],Wdc[k][2],a2);
                               a3=__builtin_fmaf(hc[k],Wdc[k][3],a3); }
        lg[2]=a2; lg[3]=a3; }
      if (u==3){
        float a4=bdr[4];
        #pragma unroll
        for (int k=0;k<8;++k) a4=__builtin_fmaf(hc[k],Wdc[k][4],a4);
        lg[4]=a4; }
      if (u==4){
        ee[0]=fexp2(lg[0]); ee[1]=fexp2(lg[1]); ee[2]=fexp2(lg[2]);
        ee[3]=fexp2(lg[3]); ee[4]=fexp2(lg[4]); }       // no max-sub: bounded
      if (u==5){
        smq=((ee[0]+ee[1])+(ee[2]+ee[3]))+ee[4]; }
      if (u==6){
        rs=frcp(smq + dppf<0xB1>(smq)); }               // combine with partner
      if (u==7){
        if (m>=1){
          outp[0]=ee[0]*rs; outp[1]=ee[1]*rs; outp[2]=ee[2]*rs;
          outp[3]=ee[3]*rs; outp[4]=ee[4]*rs;
          outp += 8*OUTN;
        } }

      pf0=pfN; tok_next=tokN;
    }
  }

  // ---- epilogue: flush octet 63 (ring slot 1) ----
  {
    const float* rv = hbuf + 384 + roff;   // (63&1)=1
    float4 a = *(const float4*)rv;
    float4 bq = *(const float4*)(rv+4);
    hc[0]=a.x; hc[1]=a.y; hc[2]=a.z; hc[3]=a.w;
    hc[4]=bq.x; hc[5]=bq.y; hc[6]=bq.z; hc[7]=bq.w;
    #pragma unroll
    for (int o=0;o<5;++o){ float aa=bdr[o];
      #pragma unroll
      for (int k=0;k<8;++k) aa=__builtin_fmaf(hc[k],Wdc[k][o],aa);
      lg[o]=aa; }
    float e0=fexp2(lg[0]), e1=fexp2(lg[1]), e2=fexp2(lg[2]),
          e3=fexp2(lg[3]), e4=fexp2(lg[4]);
    float sm=((e0+e1)+(e2+e3))+e4;
    float r=frcp(sm + dppf<0xB1>(sm));
    outp[0]=e0*r; outp[1]=e1*r; outp[2]=e2*r; outp[3]=e3*r; outp[4]=e4*r;
  }
}

// ---------------------------------------------------------------------------
// inputs: 0 tokens 1 emb 2 W 3 U 4 b 5 Wd 6 bd ; out f32 B*T*10.
// d_ws: 12800 B for the pre-scaled embW table (rewritten every call).
// ---------------------------------------------------------------------------
extern "C" void kernel_launch(void* const* d_in, const int* in_sizes, int n_in,
                              void* d_out, int out_size, void* d_ws, size_t ws_size,
                              hipStream_t stream) {
  const int*   tokens = (const int*)d_in[0];
  const float* emb    = (const float*)d_in[1];
  const float* W      = (const float*)d_in[2];
  const float* U      = (const float*)d_in[3];
  const float* b      = (const float*)d_in[4];
  const float* Wd     = (const float*)d_in[5];
  const float* bd     = (const float*)d_in[6];
  float* outp = (float*)d_out;
  float* embw = (float*)d_ws;

  embw_kernel<<<dim3(VOCABN), dim3(32), 0, stream>>>(emb, W, b, embw);
  lstm_kernel<<<dim3(BATCHN/4), dim3(64), 0, stream>>>(tokens, embw, U, Wd, bd, outp);
}